// Round 3
// baseline (2184.914 us; speedup 1.0000x reference)
//
#include <hip/hip_runtime.h>
#include <hip/hip_bf16.h>

constexpr int N_NODES = 100000;
constexpr int N_EDGES = 1600000;

// ---- workspace layout (byte offsets), total ~39.8 MB ----
constexpr size_t OFF_FLAG = 0;                              // 2 ints: [0]=fp32 floats, [1]=int32 edges
constexpr size_t OFF_DINV = 4096;                           // N fp32 (0.4 MB)
constexpr size_t OFF_WC   = 512ul * 1024;                   // 20768 fp32 (83 KB) weight/bias fp32 copies
constexpr size_t OFF_AGG  = 1024ul * 1024;                  // N*32 fp32 (12.8 MB)
constexpr size_t OFF_A    = OFF_AGG + 13ul * 1024 * 1024;   // N*64 bf16 (12.8 MB)
constexpr size_t OFF_B    = OFF_A   + 13ul * 1024 * 1024;   // N*64 bf16 (12.8 MB)

// Wc float offsets
constexpr int WC_W1 = 0, WC_W2 = 8192, WC_W3 = 10240, WC_W4 = 12288;
constexpr int WC_B1 = 20480, WC_B2 = 20544, WC_B3 = 20576, WC_B4 = 20640;
constexpr int WC_TOT = 20768;

// ---------------- dtype detection ----------------
// flags[0]=1 -> float inputs/outputs are fp32 (else bf16)
//   W1 is glorot with |w|<=0.177. bf16 buffer: low 16 bits of every word are a
//   bf16 with |v|<0.25 -> (lo&0x7F80)<0x3F00 always. fp32 buffer: lo16 is
//   uniform mantissa bits -> ~51% of words violate. 1024 words => deterministic.
// flags[1]=1 -> edge_index is int32 (else int64)
//   int64 edges: odd 32-bit words are high halves == 0. int32: odd words are
//   random node ids, nonzero essentially immediately.
__global__ void detect_kernel(const unsigned* __restrict__ w1raw,
                              const unsigned* __restrict__ eiraw,
                              int* __restrict__ flags) {
    const int t = threadIdx.x;  // 1 block x 256
    int f32 = 0, i32 = 0;
    for (int i = t; i < 1024; i += 256) {
        unsigned lo = w1raw[i] & 0xFFFFu;
        if ((lo & 0x7F80u) >= 0x3F00u) f32 = 1;
    }
    for (int i = t; i < 4096; i += 256)
        if ((i & 1) && eiraw[i] != 0u) i32 = 1;
    if (f32) atomicOr(&flags[0], 1);
    if (i32) atomicOr(&flags[1], 1);
}

__device__ __forceinline__ unsigned edge_src(const int* ei, int i64, int e) {
    return (unsigned)(i64 ? ei[2 * (size_t)e] : ei[e]);
}
__device__ __forceinline__ unsigned edge_dst(const int* ei, int i64, int e) {
    return (unsigned)(i64 ? ei[2 * (size_t)N_EDGES + 2 * (size_t)e]
                          : ei[(size_t)N_EDGES + e]);
}

// ---------------- weights -> fp32 ws copies ----------------
__global__ void convw_kernel(const void* W1, const void* b1, const void* W2, const void* b2,
                             const void* W3, const void* b3, const void* W4, const void* b4,
                             const int* __restrict__ flags, float* __restrict__ Wc) {
    int i = blockIdx.x * blockDim.x + threadIdx.x;
    if (i >= WC_TOT) return;
    const void* src; int off;
    if      (i < WC_W2) { src = W1; off = i; }
    else if (i < WC_W3) { src = W2; off = i - WC_W2; }
    else if (i < WC_W4) { src = W3; off = i - WC_W3; }
    else if (i < WC_B1) { src = W4; off = i - WC_W4; }
    else if (i < WC_B2) { src = b1; off = i - WC_B1; }
    else if (i < WC_B3) { src = b2; off = i - WC_B2; }
    else if (i < WC_B4) { src = b3; off = i - WC_B3; }
    else                { src = b4; off = i - WC_B4; }
    Wc[i] = flags[0] ? ((const float*)src)[off]
                     : __bfloat162float(((const __hip_bfloat16*)src)[off]);
}

// ---------------- degree / normalization ----------------
__global__ void deg_kernel(const int* __restrict__ ei, const int* __restrict__ flags,
                           float* __restrict__ deg) {
    int e = blockIdx.x * blockDim.x + threadIdx.x;
    if (e >= N_EDGES) return;
    const int i64 = (flags[1] == 0);
    unsigned d = edge_dst(ei, i64, e);
    if (d < (unsigned)N_NODES) atomicAdd(&deg[d], 1.0f);
}

__global__ void dinv_kernel(float* __restrict__ deg) {
    int n = blockIdx.x * blockDim.x + threadIdx.x;
    if (n < N_NODES) deg[n] = rsqrtf(deg[n] + 1.0f);
}

// ---------------- dense: out = in @ Wc[:, wcol0:wcol0+OUT] (fp32 accum, bf16 out) ----------------
template <int IN, int OUT, int ILD, int OLD, int WLD, bool DYN>
__global__ void gemm_kernel(const void* __restrict__ in, const int* __restrict__ flags,
                            const float* __restrict__ Wc, int wcol0,
                            __hip_bfloat16* __restrict__ out) {
    constexpr int NP = 256 / OUT;  // nodes per block
    __shared__ float Ws[IN * OUT];
    __shared__ float Xs[NP * IN];
    const int tid = threadIdx.x;
    const int f32 = DYN ? flags[0] : 0;
    for (int i = tid; i < IN * OUT; i += 256) {
        int k = i / OUT, c = i % OUT;
        Ws[i] = Wc[k * WLD + wcol0 + c];
    }
    const int nbase = blockIdx.x * NP;
    for (int i = tid; i < NP * IN; i += 256) {
        int ln = i / IN, k = i % IN;
        int n = nbase + ln;
        float v = 0.0f;
        if (n < N_NODES) {
            if (DYN && f32) v = ((const float*)in)[(size_t)n * ILD + k];
            else            v = __bfloat162float(((const __hip_bfloat16*)in)[(size_t)n * ILD + k]);
        }
        Xs[i] = v;
    }
    __syncthreads();
    const int ln = tid / OUT, col = tid % OUT;
    const int n = nbase + ln;
    if (n >= N_NODES) return;
    float sum = 0.0f;
#pragma unroll
    for (int k = 0; k < IN; ++k)
        sum = fmaf(Xs[ln * IN + k], Ws[k * OUT + col], sum);
    out[(size_t)n * OLD + col] = __float2bfloat16(sum);
}

// ---------------- edge scatter (32-col chunk): agg[d,j] += h[s, hcol0+j]*dinv[s]*dinv[d] ----
__global__ void scatter_kernel(const int* __restrict__ ei, const int* __restrict__ flags,
                               const float* __restrict__ dinv,
                               const __hip_bfloat16* __restrict__ h, int hLD, int hcol0,
                               float* __restrict__ agg) {
    const long long t = (long long)blockIdx.x * 256 + threadIdx.x;
    const int e = (int)(t >> 5);
    const int j = (int)(t & 31);
    if (e >= N_EDGES) return;
    const int i64 = (flags[1] == 0);
    const unsigned s = edge_src(ei, i64, e);
    const unsigned d = edge_dst(ei, i64, e);
    if (s >= (unsigned)N_NODES || d >= (unsigned)N_NODES) return;  // safety guard
    const float ne = dinv[s] * dinv[d];
    atomicAdd(&agg[(size_t)d * 32 + j],
              __bfloat162float(h[(size_t)s * hLD + hcol0 + j]) * ne);
}

// ---------------- finalize (32-col chunk): v = agg + h*dinv^2 + b [+relu] ----------------
template <bool RELU>
__global__ void finalize_kernel(const float* __restrict__ agg,
                                const __hip_bfloat16* __restrict__ h, int hLD, int hcol0,
                                const float* __restrict__ dinv,
                                const float* __restrict__ b,           // bias segment + col base
                                __hip_bfloat16* __restrict__ wsdst, int wsLD, int wscol0,
                                void* __restrict__ gout, size_t gbase, int gLD, int gcol0,
                                const int* __restrict__ flags) {
    const int t = blockIdx.x * 256 + threadIdx.x;
    if (t >= N_NODES * 32) return;
    const int n = t >> 5, j = t & 31;
    const float di = dinv[n];
    float v = agg[t] + __bfloat162float(h[(size_t)n * hLD + hcol0 + j]) * (di * di) + b[j];
    if (RELU) v = fmaxf(v, 0.0f);
    if (wsdst) wsdst[(size_t)n * wsLD + wscol0 + j] = __float2bfloat16(v);
    if (gout) {
        size_t idx = gbase + (size_t)n * gLD + gcol0 + j;
        if (flags[0]) ((float*)gout)[idx] = v;
        else          ((__hip_bfloat16*)gout)[idx] = __float2bfloat16(v);
    }
}

// ---------------- launch ----------------
extern "C" void kernel_launch(void* const* d_in, const int* in_sizes, int n_in,
                              void* d_out, int out_size, void* d_ws, size_t ws_size,
                              hipStream_t stream) {
    const void* x  = d_in[0];
    const int* ei  = (const int*)d_in[1];
    const void* W1 = d_in[2]; const void* b1 = d_in[3];
    const void* W2 = d_in[4]; const void* b2 = d_in[5];
    const void* W3 = d_in[6]; const void* b3 = d_in[7];
    const void* W4 = d_in[8]; const void* b4 = d_in[9];

    char* ws = (char*)d_ws;
    int*   flags = (int*)(ws + OFF_FLAG);
    float* dinv  = (float*)(ws + OFF_DINV);
    float* Wc    = (float*)(ws + OFF_WC);
    float* agg   = (float*)(ws + OFF_AGG);
    __hip_bfloat16* A = (__hip_bfloat16*)(ws + OFF_A);
    __hip_bfloat16* B = (__hip_bfloat16*)(ws + OFF_B);

    const int SCAT = (int)(((size_t)N_EDGES * 32) / 256);   // 200000, exact
    const int FIN  = (N_NODES * 32 + 255) / 256;            // 12500
    const size_t AGG_B = (size_t)N_NODES * 32 * sizeof(float);

    // flags + dtype detection + weight conversion
    hipMemsetAsync(flags, 0, 2 * sizeof(int), stream);
    detect_kernel<<<1, 256, 0, stream>>>((const unsigned*)W1, (const unsigned*)ei, flags);
    convw_kernel<<<(WC_TOT + 255) / 256, 256, 0, stream>>>(W1, b1, W2, b2, W3, b3, W4, b4,
                                                           flags, Wc);
    // degrees -> dinv
    hipMemsetAsync(dinv, 0, (size_t)N_NODES * sizeof(float), stream);
    deg_kernel<<<(N_EDGES + 255) / 256, 256, 0, stream>>>(ei, flags, dinv);
    dinv_kernel<<<(N_NODES + 255) / 256, 256, 0, stream>>>(dinv);

    // ---- Layer 1: 128 -> 64, ReLU.  x -> A (h), finalize -> B ----
    gemm_kernel<128, 64, 128, 64, 64, true><<<(N_NODES + 3) / 4, 256, 0, stream>>>(
        x, flags, Wc + WC_W1, 0, A);
    for (int c = 0; c < 64; c += 32) {
        hipMemsetAsync(agg, 0, AGG_B, stream);
        scatter_kernel<<<SCAT, 256, 0, stream>>>(ei, flags, dinv, A, 64, c, agg);
        finalize_kernel<true><<<FIN, 256, 0, stream>>>(agg, A, 64, c, dinv, Wc + WC_B1 + c,
                                                       B, 64, c, nullptr, 0, 0, 0, flags);
    }

    // ---- Layer 2: 64 -> 32 (z).  B -> A (h), finalize -> B(N x 32) + out_z ----
    gemm_kernel<64, 32, 64, 32, 32, false><<<(N_NODES + 7) / 8, 256, 0, stream>>>(
        B, flags, Wc + WC_W2, 0, A);
    {
        hipMemsetAsync(agg, 0, AGG_B, stream);
        scatter_kernel<<<SCAT, 256, 0, stream>>>(ei, flags, dinv, A, 32, 0, agg);
        finalize_kernel<false><<<FIN, 256, 0, stream>>>(agg, A, 32, 0, dinv, Wc + WC_B2,
                                                        B, 32, 0,
                                                        d_out, (size_t)N_NODES * 128, 32, 0, flags);
    }

    // ---- Layer 3: 32 -> 64, ReLU.  B(z) -> A (h), finalize -> B(N x 64) ----
    gemm_kernel<32, 64, 32, 64, 64, false><<<(N_NODES + 3) / 4, 256, 0, stream>>>(
        B, flags, Wc + WC_W3, 0, A);
    for (int c = 0; c < 64; c += 32) {
        hipMemsetAsync(agg, 0, AGG_B, stream);
        scatter_kernel<<<SCAT, 256, 0, stream>>>(ei, flags, dinv, A, 64, c, agg);
        finalize_kernel<true><<<FIN, 256, 0, stream>>>(agg, A, 64, c, dinv, Wc + WC_B3 + c,
                                                       B, 64, c, nullptr, 0, 0, 0, flags);
    }

    // ---- Layer 4: 64 -> 128 in two 64-col halves.  B -> A (h), finalize -> x_rec ----
    for (int half = 0; half < 2; ++half) {
        const int h0 = half * 64;
        gemm_kernel<64, 64, 64, 64, 128, false><<<(N_NODES + 3) / 4, 256, 0, stream>>>(
            B, flags, Wc + WC_W4, h0, A);
        for (int c = 0; c < 64; c += 32) {
            hipMemsetAsync(agg, 0, AGG_B, stream);
            scatter_kernel<<<SCAT, 256, 0, stream>>>(ei, flags, dinv, A, 64, c, agg);
            finalize_kernel<false><<<FIN, 256, 0, stream>>>(agg, A, 64, c, dinv,
                                                            Wc + WC_B4 + h0 + c,
                                                            nullptr, 0, 0,
                                                            d_out, 0, 128, h0 + c, flags);
        }
    }
}

// Round 4
// 904.942 us; speedup vs baseline: 2.4144x; 2.4144x over previous
//
#include <hip/hip_runtime.h>
#include <hip/hip_bf16.h>

constexpr int N_NODES = 100000;
constexpr int N_EDGES = 1600000;
constexpr int SCAN_B  = 1024;
constexpr int SCAN_G  = (N_NODES + SCAN_B) / SCAN_B;   // 98 blocks covers N+1 elements

// ---- workspace layout (byte offsets), total ~33.3 MB ----
constexpr size_t OFF_FLAG = 0;                 // 2 ints: [0]=fp32 floats, [1]=int32 edges
constexpr size_t OFF_DEG  = 4    * 1024;       // int[N]      (400 KB)
constexpr size_t OFF_DINV = 408  * 1024;       // float[N]    (400 KB)
constexpr size_t OFF_OFFS = 812  * 1024;       // int[N+1]    (400 KB)
constexpr size_t OFF_CURS = 1216 * 1024;       // int[N]      (400 KB)
constexpr size_t OFF_BSUM = 1620 * 1024;       // int[128] bsum + int[128] boff
constexpr size_t OFF_WC   = 1624 * 1024;       // float[20768] (83 KB)
constexpr size_t OFF_CSR  = 1712 * 1024;       // int[E]      (6.4 MB)
constexpr size_t OFF_A    = 8192 * 1024;       // bf16 N*64 h' buffer (12.8 MB)
constexpr size_t OFF_B    = 21504 * 1024;      // bf16 N*64 activation buffer (12.8 MB)

// Wc float offsets
constexpr int WC_W1 = 0, WC_W2 = 8192, WC_W3 = 10240, WC_W4 = 12288;
constexpr int WC_B1 = 20480, WC_B2 = 20544, WC_B3 = 20576, WC_B4 = 20640;
constexpr int WC_TOT = 20768;

// ---------------- dtype detection (proven in round 3) ----------------
__global__ void detect_kernel(const unsigned* __restrict__ w1raw,
                              const unsigned* __restrict__ eiraw,
                              int* __restrict__ flags) {
    const int t = threadIdx.x;  // 1 block x 256
    int f32 = 0, i32 = 0;
    for (int i = t; i < 1024; i += 256) {
        unsigned lo = w1raw[i] & 0xFFFFu;
        if ((lo & 0x7F80u) >= 0x3F00u) f32 = 1;    // bf16 glorot can't have big low-half exp
    }
    for (int i = t; i < 4096; i += 256)
        if ((i & 1) && eiraw[i] != 0u) i32 = 1;    // int64 high words are all zero
    if (f32) atomicOr(&flags[0], 1);
    if (i32) atomicOr(&flags[1], 1);
}

__device__ __forceinline__ unsigned edge_src(const int* ei, int i64, int e) {
    return (unsigned)(i64 ? ei[2 * (size_t)e] : ei[e]);
}
__device__ __forceinline__ unsigned edge_dst(const int* ei, int i64, int e) {
    return (unsigned)(i64 ? ei[2 * (size_t)N_EDGES + 2 * (size_t)e]
                          : ei[(size_t)N_EDGES + e]);
}

// ---------------- weights -> fp32 ws copies ----------------
__global__ void convw_kernel(const void* W1, const void* b1, const void* W2, const void* b2,
                             const void* W3, const void* b3, const void* W4, const void* b4,
                             const int* __restrict__ flags, float* __restrict__ Wc) {
    int i = blockIdx.x * blockDim.x + threadIdx.x;
    if (i >= WC_TOT) return;
    const void* src; int off;
    if      (i < WC_W2) { src = W1; off = i; }
    else if (i < WC_W3) { src = W2; off = i - WC_W2; }
    else if (i < WC_W4) { src = W3; off = i - WC_W3; }
    else if (i < WC_B1) { src = W4; off = i - WC_W4; }
    else if (i < WC_B2) { src = b1; off = i - WC_B1; }
    else if (i < WC_B3) { src = b2; off = i - WC_B2; }
    else if (i < WC_B4) { src = b3; off = i - WC_B3; }
    else                { src = b4; off = i - WC_B4; }
    Wc[i] = flags[0] ? ((const float*)src)[off]
                     : __bfloat162float(((const __hip_bfloat16*)src)[off]);
}

// ---------------- degree histogram (int) ----------------
__global__ void deg_kernel(const int* __restrict__ ei, const int* __restrict__ flags,
                           int* __restrict__ deg) {
    int e = blockIdx.x * blockDim.x + threadIdx.x;
    if (e >= N_EDGES) return;
    const int i64 = (flags[1] == 0);
    unsigned d = edge_dst(ei, i64, e);
    if (d < (unsigned)N_NODES) atomicAdd(&deg[d], 1);
}

__global__ void dinv_kernel(const int* __restrict__ deg, float* __restrict__ dinv) {
    int n = blockIdx.x * blockDim.x + threadIdx.x;
    if (n < N_NODES) dinv[n] = rsqrtf((float)deg[n] + 1.0f);
}

// ---------------- hierarchical exclusive scan of deg -> offsets ----------------
__global__ __launch_bounds__(1024) void scan1_kernel(const int* __restrict__ deg,
                                                     int* __restrict__ bsum) {
    const int i = blockIdx.x * SCAN_B + threadIdx.x;
    const int lane = threadIdx.x & 63, wid = threadIdx.x >> 6;
    int v = (i < N_NODES) ? deg[i] : 0;
    for (int o = 32; o > 0; o >>= 1) v += __shfl_down(v, o, 64);
    __shared__ int ws[16];
    if (lane == 0) ws[wid] = v;
    __syncthreads();
    if (wid == 0) {
        int t = (lane < 16) ? ws[lane] : 0;
        for (int o = 8; o > 0; o >>= 1) t += __shfl_down(t, o, 64);
        if (lane == 0) bsum[blockIdx.x] = t;
    }
}

__global__ void scan2_kernel(const int* __restrict__ bsum, int* __restrict__ boff) {
    const int t = threadIdx.x;   // 1 block x 128
    __shared__ int tmp[128];
    int v = (t < SCAN_G) ? bsum[t] : 0;
    tmp[t] = v;
    __syncthreads();
    for (int o = 1; o < 128; o <<= 1) {
        int a = (t >= o) ? tmp[t - o] : 0;
        __syncthreads();
        tmp[t] += a;
        __syncthreads();
    }
    boff[t] = tmp[t] - v;        // exclusive
}

__global__ __launch_bounds__(1024) void scan3_kernel(const int* __restrict__ deg,
                                                     const int* __restrict__ boff,
                                                     int* __restrict__ offs,
                                                     int* __restrict__ curs) {
    const int i = blockIdx.x * SCAN_B + threadIdx.x;
    const int lane = threadIdx.x & 63, wid = threadIdx.x >> 6;
    int v = (i < N_NODES) ? deg[i] : 0;
    int incl = v;
    for (int o = 1; o < 64; o <<= 1) {
        int t = __shfl_up(incl, (unsigned)o, 64);
        if (lane >= o) incl += t;
    }
    __shared__ int wsum[16], woff[16];
    if (lane == 63) wsum[wid] = incl;
    __syncthreads();
    if (wid == 0 && lane < 16) {
        int u = wsum[lane];
        int uin = u;
        for (int o = 1; o < 16; o <<= 1) {
            int t = __shfl_up(uin, (unsigned)o, 64);
            if (lane >= o) uin += t;
        }
        woff[lane] = uin - u;
    }
    __syncthreads();
    const int excl = incl - v + woff[wid] + boff[blockIdx.x];
    if (i <= N_NODES) {
        offs[i] = excl;
        if (i < N_NODES) curs[i] = excl;
    }
}

// ---------------- CSR fill: csr[curs[d]++] = s ----------------
__global__ void fill_kernel(const int* __restrict__ ei, const int* __restrict__ flags,
                            int* __restrict__ curs, int* __restrict__ csr) {
    int e = blockIdx.x * blockDim.x + threadIdx.x;
    if (e >= N_EDGES) return;
    const int i64 = (flags[1] == 0);
    unsigned s = edge_src(ei, i64, e);
    unsigned d = edge_dst(ei, i64, e);
    if (s >= (unsigned)N_NODES || d >= (unsigned)N_NODES) return;
    int pos = atomicAdd(&curs[d], 1);
    if ((unsigned)pos < (unsigned)N_EDGES) csr[pos] = (int)s;
}

// ---------------- register-blocked GEMM: h' = (in @ Wc[:,wcol0:+OUT]) * dinv, bf16 out ----
// Block: NBLK nodes x OUT cols, threads = (NBLK/4)*(OUT/4), each thread a 4x4 tile.
template <int IN, int OUT, int NBLK, bool DYNIN>
__global__ void gemm_kernel(const void* __restrict__ in, int inLD,
                            const int* __restrict__ flags,
                            const float* __restrict__ Wc, int WLD, int wcol0,
                            const float* __restrict__ dinv,
                            __hip_bfloat16* __restrict__ out) {
    constexpr int XLD = IN + 1;                   // +1 pad: bank-conflict-free column reads
    constexpr int NT  = (NBLK / 4) * (OUT / 4);
    __shared__ float Xs[NBLK * XLD];
    __shared__ float Ws[IN * OUT];
    const int tid = threadIdx.x;
    const int f32 = DYNIN ? flags[0] : 0;
    const int nbase = blockIdx.x * NBLK;
    for (int i = tid; i < IN * OUT; i += NT) {
        int k = i / OUT, c = i % OUT;
        Ws[i] = Wc[k * WLD + wcol0 + c];
    }
    for (int i = tid; i < NBLK * IN; i += NT) {
        int nl = i / IN, k = i % IN;
        int n = nbase + nl;
        float v = 0.0f;
        if (n < N_NODES) {
            if (DYNIN && f32) v = ((const float*)in)[(size_t)n * inLD + k];
            else v = __bfloat162float(((const __hip_bfloat16*)in)[(size_t)n * inLD + k]);
        }
        Xs[nl * XLD + k] = v;
    }
    __syncthreads();
    const int gc = tid % (OUT / 4);
    const int gn = tid / (OUT / 4);
    float acc[4][4] = {};
    for (int k = 0; k < IN; ++k) {
        const float4 w = *(const float4*)&Ws[k * OUT + gc * 4];
#pragma unroll
        for (int i = 0; i < 4; ++i) {
            const float xv = Xs[(gn * 4 + i) * XLD + k];
            acc[i][0] = fmaf(xv, w.x, acc[i][0]);
            acc[i][1] = fmaf(xv, w.y, acc[i][1]);
            acc[i][2] = fmaf(xv, w.z, acc[i][2]);
            acc[i][3] = fmaf(xv, w.w, acc[i][3]);
        }
    }
#pragma unroll
    for (int i = 0; i < 4; ++i) {
        const int n = nbase + gn * 4 + i;
        if (n >= N_NODES) continue;
        const float sc = dinv[n];
        __hip_bfloat162 p0, p1;
        p0.x = __float2bfloat16(acc[i][0] * sc);
        p0.y = __float2bfloat16(acc[i][1] * sc);
        p1.x = __float2bfloat16(acc[i][2] * sc);
        p1.y = __float2bfloat16(acc[i][3] * sc);
        __hip_bfloat162* dst = (__hip_bfloat162*)&out[(size_t)n * OUT + gc * 4];
        dst[0] = p0;
        dst[1] = p1;
    }
}

// ---------------- CSR aggregation: out[n] = dinv[n]*(sum_{s in N(n)} h'[s] + h'[n]) + b ----
// One wave per node; lane = column (D=32: upper half mirrors, only lanes<32 store).
template <int D, bool RELU>
__global__ void agg_kernel(const int* __restrict__ offs, const int* __restrict__ csr,
                           const float* __restrict__ dinv,
                           const __hip_bfloat16* __restrict__ h,   // N x D, dinv-prescaled
                           const float* __restrict__ bias,
                           __hip_bfloat16* __restrict__ wsout,     // N x D bf16, or null
                           void* __restrict__ gout, size_t gbase, int gLD, int gcol0,
                           const int* __restrict__ flags) {
    const int lane = threadIdx.x & 63;
    const int n = blockIdx.x * 4 + (threadIdx.x >> 6);
    if (n >= N_NODES) return;
    const int col = (D == 64) ? lane : (lane & 31);
    float acc = __bfloat162float(h[(size_t)n * D + col]);   // self-loop term
    const int o0 = offs[n], o1 = offs[n + 1];
    for (int base = o0; base < o1; base += 64) {
        const int idx = base + lane;
        const int sid = (idx < o1) ? csr[idx] : 0;
        const int cnt = min(64, o1 - base);
        int k = 0;
        for (; k + 4 <= cnt; k += 4) {
            const int s0 = __shfl(sid, k + 0, 64);
            const int s1 = __shfl(sid, k + 1, 64);
            const int s2 = __shfl(sid, k + 2, 64);
            const int s3 = __shfl(sid, k + 3, 64);
            const float v0 = __bfloat162float(h[(size_t)s0 * D + col]);
            const float v1 = __bfloat162float(h[(size_t)s1 * D + col]);
            const float v2 = __bfloat162float(h[(size_t)s2 * D + col]);
            const float v3 = __bfloat162float(h[(size_t)s3 * D + col]);
            acc += (v0 + v1) + (v2 + v3);
        }
        for (; k < cnt; ++k) {
            const int s = __shfl(sid, k, 64);
            acc += __bfloat162float(h[(size_t)s * D + col]);
        }
    }
    float v = fmaf(acc, dinv[n], bias[col]);
    if (RELU) v = fmaxf(v, 0.0f);
    if (D == 32 && lane >= 32) return;
    if (wsout) wsout[(size_t)n * D + col] = __float2bfloat16(v);
    if (gout) {
        const size_t gi = gbase + (size_t)n * gLD + gcol0 + col;
        if (flags[0]) ((float*)gout)[gi] = v;
        else          ((__hip_bfloat16*)gout)[gi] = __float2bfloat16(v);
    }
}

// ---------------- launch ----------------
extern "C" void kernel_launch(void* const* d_in, const int* in_sizes, int n_in,
                              void* d_out, int out_size, void* d_ws, size_t ws_size,
                              hipStream_t stream) {
    const void* x  = d_in[0];
    const int* ei  = (const int*)d_in[1];
    const void* W1 = d_in[2]; const void* b1 = d_in[3];
    const void* W2 = d_in[4]; const void* b2 = d_in[5];
    const void* W3 = d_in[6]; const void* b3 = d_in[7];
    const void* W4 = d_in[8]; const void* b4 = d_in[9];

    char* ws = (char*)d_ws;
    int*   flags = (int*)(ws + OFF_FLAG);
    int*   deg   = (int*)(ws + OFF_DEG);
    float* dinv  = (float*)(ws + OFF_DINV);
    int*   offs  = (int*)(ws + OFF_OFFS);
    int*   curs  = (int*)(ws + OFF_CURS);
    int*   bsum  = (int*)(ws + OFF_BSUM);
    int*   boff  = bsum + 128;
    float* Wc    = (float*)(ws + OFF_WC);
    int*   csr   = (int*)(ws + OFF_CSR);
    __hip_bfloat16* A = (__hip_bfloat16*)(ws + OFF_A);
    __hip_bfloat16* B = (__hip_bfloat16*)(ws + OFF_B);

    const int EB = (N_EDGES + 255) / 256;

    // setup: flags, weights, degrees, dinv, CSR
    hipMemsetAsync(flags, 0, 2 * sizeof(int), stream);
    hipMemsetAsync(deg, 0, (size_t)N_NODES * sizeof(int), stream);
    detect_kernel<<<1, 256, 0, stream>>>((const unsigned*)W1, (const unsigned*)ei, flags);
    convw_kernel<<<(WC_TOT + 255) / 256, 256, 0, stream>>>(W1, b1, W2, b2, W3, b3, W4, b4,
                                                           flags, Wc);
    deg_kernel<<<EB, 256, 0, stream>>>(ei, flags, deg);
    dinv_kernel<<<(N_NODES + 255) / 256, 256, 0, stream>>>(deg, dinv);
    scan1_kernel<<<SCAN_G, SCAN_B, 0, stream>>>(deg, bsum);
    scan2_kernel<<<1, 128, 0, stream>>>(bsum, boff);
    scan3_kernel<<<SCAN_G, SCAN_B, 0, stream>>>(deg, boff, offs, curs);
    fill_kernel<<<EB, 256, 0, stream>>>(ei, flags, curs, csr);

    const int AGG_G = N_NODES / 4;   // 25000, exact

    // ---- Layer 1: 128 -> 64, ReLU.  x -> A (h'), aggregate -> B (act1) ----
    gemm_kernel<128, 64, 32, true><<<(N_NODES + 31) / 32, 128, 0, stream>>>(
        x, 128, flags, Wc + WC_W1, 64, 0, dinv, A);
    agg_kernel<64, true><<<AGG_G, 256, 0, stream>>>(offs, csr, dinv, A, Wc + WC_B1,
                                                    B, nullptr, 0, 0, 0, flags);

    // ---- Layer 2: 64 -> 32 (z).  B -> A (h'), aggregate -> B (z) + d_out z ----
    gemm_kernel<64, 32, 64, false><<<(N_NODES + 63) / 64, 128, 0, stream>>>(
        B, 64, flags, Wc + WC_W2, 32, 0, dinv, A);
    agg_kernel<32, false><<<AGG_G, 256, 0, stream>>>(offs, csr, dinv, A, Wc + WC_B2,
                                                     B, d_out, (size_t)N_NODES * 128, 32, 0,
                                                     flags);

    // ---- Layer 3: 32 -> 64, ReLU.  B (z) -> A (h'), aggregate -> B (act3) ----
    gemm_kernel<32, 64, 64, false><<<(N_NODES + 63) / 64, 256, 0, stream>>>(
        B, 32, flags, Wc + WC_W3, 64, 0, dinv, A);
    agg_kernel<64, true><<<AGG_G, 256, 0, stream>>>(offs, csr, dinv, A, Wc + WC_B3,
                                                    B, nullptr, 0, 0, 0, flags);

    // ---- Layer 4: 64 -> 128 in two 64-col halves.  B -> A (h'), aggregate -> x_rec ----
    for (int half = 0; half < 2; ++half) {
        const int h0 = half * 64;
        gemm_kernel<64, 64, 64, false><<<(N_NODES + 63) / 64, 256, 0, stream>>>(
            B, 64, flags, Wc + WC_W4, 128, h0, dinv, A);
        agg_kernel<64, false><<<AGG_G, 256, 0, stream>>>(offs, csr, dinv, A, Wc + WC_B4 + h0,
                                                         nullptr, d_out, 0, 128, h0, flags);
    }
}

// Round 5
// 681.518 us; speedup vs baseline: 3.2060x; 1.3278x over previous
//
#include <hip/hip_runtime.h>
#include <hip/hip_bf16.h>

constexpr int N_NODES = 100000;
constexpr int N_EDGES = 1600000;
constexpr int SCAN_B  = 1024;
constexpr int SCAN_G  = (N_NODES + SCAN_B) / SCAN_B;   // 98 blocks covers N+1 elements
constexpr int FCH     = 8192;                          // edges per chunk (slice kernels)
constexpr int NCH     = (N_EDGES + FCH - 1) / FCH;     // 196
constexpr int SLICE_N = N_NODES / 8;                   // 12500 (8*12500 == N exactly)

// ---- workspace layout (byte offsets), total ~47.7 MB ----
constexpr size_t OFF_FLAG = 0;                 // 2 ints: [0]=fp32 floats, [1]=int32 edges
constexpr size_t OFF_DEG  = 4    * 1024;       // int[N]
constexpr size_t OFF_DINV = 408  * 1024;       // float[N]
constexpr size_t OFF_OFFS = 812  * 1024;       // int[N+1]
constexpr size_t OFF_CURS = 1216 * 1024;       // int[N]
constexpr size_t OFF_BSUM = 1620 * 1024;       // int[128] bsum + int[128] boff
constexpr size_t OFF_WC   = 1624 * 1024;       // float[20768]
constexpr size_t OFF_CSR  = 1712 * 1024;       // int[E] (6.4 MB)
constexpr size_t OFF_A    = 8192 * 1024;       // bf16 N*128 h' buffer (25.6 MB)
constexpr size_t OFF_B    = 34816ul * 1024;    // bf16 N*64 activation buffer (12.8 MB)

// Wc float offsets
constexpr int WC_W1 = 0, WC_W2 = 8192, WC_W3 = 10240, WC_W4 = 12288;
constexpr int WC_B1 = 20480, WC_B2 = 20544, WC_B3 = 20576, WC_B4 = 20640;
constexpr int WC_TOT = 20768;

__device__ __forceinline__ float bf2f(unsigned short b) {
    union { unsigned u; float f; } c; c.u = ((unsigned)b) << 16; return c.f;
}

// ---------------- dtype detection (proven) ----------------
__global__ void detect_kernel(const unsigned* __restrict__ w1raw,
                              const unsigned* __restrict__ eiraw,
                              int* __restrict__ flags) {
    const int t = threadIdx.x;  // 1 block x 256
    int f32 = 0, i32 = 0;
    for (int i = t; i < 1024; i += 256) {
        unsigned lo = w1raw[i] & 0xFFFFu;
        if ((lo & 0x7F80u) >= 0x3F00u) f32 = 1;    // bf16 glorot can't have big low-half exp
    }
    for (int i = t; i < 4096; i += 256)
        if ((i & 1) && eiraw[i] != 0u) i32 = 1;    // int64 high words are all zero
    if (f32) atomicOr(&flags[0], 1);
    if (i32) atomicOr(&flags[1], 1);
}

__device__ __forceinline__ unsigned edge_src(const int* ei, int i64, int e) {
    return (unsigned)(i64 ? ei[2 * (size_t)e] : ei[e]);
}
__device__ __forceinline__ unsigned edge_dst(const int* ei, int i64, int e) {
    return (unsigned)(i64 ? ei[2 * (size_t)N_EDGES + 2 * (size_t)e]
                          : ei[(size_t)N_EDGES + e]);
}

// ---------------- weights -> fp32 ws copies ----------------
__global__ void convw_kernel(const void* W1, const void* b1, const void* W2, const void* b2,
                             const void* W3, const void* b3, const void* W4, const void* b4,
                             const int* __restrict__ flags, float* __restrict__ Wc) {
    int i = blockIdx.x * blockDim.x + threadIdx.x;
    if (i >= WC_TOT) return;
    const void* src; int off;
    if      (i < WC_W2) { src = W1; off = i; }
    else if (i < WC_W3) { src = W2; off = i - WC_W2; }
    else if (i < WC_W4) { src = W3; off = i - WC_W3; }
    else if (i < WC_B1) { src = W4; off = i - WC_W4; }
    else if (i < WC_B2) { src = b1; off = i - WC_B1; }
    else if (i < WC_B3) { src = b2; off = i - WC_B2; }
    else if (i < WC_B4) { src = b3; off = i - WC_B3; }
    else                { src = b4; off = i - WC_B4; }
    Wc[i] = flags[0] ? ((const float*)src)[off]
                     : __bfloat162float(((const __hip_bfloat16*)src)[off]);
}

// ---------------- slice-local degree histogram ----------------
// block b: slice = b&7 (XCD round-robin), chunk = b>>3. Atomics confined to a
// 50 KB deg slice -> stays in one XCD L2 instead of line-ping-pong across 8.
__global__ void deg_kernel(const int* __restrict__ ei, const int* __restrict__ flags,
                           int* __restrict__ deg) {
    const int slice = blockIdx.x & 7;
    const int chunk = blockIdx.x >> 3;
    const int i64 = (flags[1] == 0);
    const unsigned lo = (unsigned)(slice * SLICE_N);
    const int e0 = chunk * FCH;
    const int e1 = min(e0 + FCH, N_EDGES);
    for (int e = e0 + threadIdx.x; e < e1; e += 256) {
        unsigned d = edge_dst(ei, i64, e);
        if (d - lo < (unsigned)SLICE_N && d < (unsigned)N_NODES) atomicAdd(&deg[d], 1);
    }
}

__global__ void dinv_kernel(const int* __restrict__ deg, float* __restrict__ dinv) {
    int n = blockIdx.x * blockDim.x + threadIdx.x;
    if (n < N_NODES) dinv[n] = rsqrtf((float)deg[n] + 1.0f);
}

// ---------------- hierarchical exclusive scan of deg -> offsets ----------------
__global__ __launch_bounds__(1024) void scan1_kernel(const int* __restrict__ deg,
                                                     int* __restrict__ bsum) {
    const int i = blockIdx.x * SCAN_B + threadIdx.x;
    const int lane = threadIdx.x & 63, wid = threadIdx.x >> 6;
    int v = (i < N_NODES) ? deg[i] : 0;
    for (int o = 32; o > 0; o >>= 1) v += __shfl_down(v, o, 64);
    __shared__ int ws[16];
    if (lane == 0) ws[wid] = v;
    __syncthreads();
    if (wid == 0) {
        int t = (lane < 16) ? ws[lane] : 0;
        for (int o = 8; o > 0; o >>= 1) t += __shfl_down(t, o, 64);
        if (lane == 0) bsum[blockIdx.x] = t;
    }
}

__global__ void scan2_kernel(const int* __restrict__ bsum, int* __restrict__ boff) {
    const int t = threadIdx.x;   // 1 block x 128
    __shared__ int tmp[128];
    int v = (t < SCAN_G) ? bsum[t] : 0;
    tmp[t] = v;
    __syncthreads();
    for (int o = 1; o < 128; o <<= 1) {
        int a = (t >= o) ? tmp[t - o] : 0;
        __syncthreads();
        tmp[t] += a;
        __syncthreads();
    }
    boff[t] = tmp[t] - v;        // exclusive
}

__global__ __launch_bounds__(1024) void scan3_kernel(const int* __restrict__ deg,
                                                     const int* __restrict__ boff,
                                                     int* __restrict__ offs,
                                                     int* __restrict__ curs) {
    const int i = blockIdx.x * SCAN_B + threadIdx.x;
    const int lane = threadIdx.x & 63, wid = threadIdx.x >> 6;
    int v = (i < N_NODES) ? deg[i] : 0;
    int incl = v;
    for (int o = 1; o < 64; o <<= 1) {
        int t = __shfl_up(incl, (unsigned)o, 64);
        if (lane >= o) incl += t;
    }
    __shared__ int wsum[16], woff[16];
    if (lane == 63) wsum[wid] = incl;
    __syncthreads();
    if (wid == 0 && lane < 16) {
        int u = wsum[lane];
        int uin = u;
        for (int o = 1; o < 16; o <<= 1) {
            int t = __shfl_up(uin, (unsigned)o, 64);
            if (lane >= o) uin += t;
        }
        woff[lane] = uin - u;
    }
    __syncthreads();
    const int excl = incl - v + woff[wid] + boff[blockIdx.x];
    if (i <= N_NODES) {
        offs[i] = excl;
        if (i < N_NODES) curs[i] = excl;
    }
}

// ---------------- slice-local CSR fill ----------------
// Same slice structure as deg_kernel: csr writes for slice s land in the
// contiguous [offs[s*SLICE_N], offs[(s+1)*SLICE_N]) region (~800 KB) -> one
// XCD's L2, full-line accumulation before eviction.
__global__ void fill_kernel(const int* __restrict__ ei, const int* __restrict__ flags,
                            int* __restrict__ curs, int* __restrict__ csr) {
    const int slice = blockIdx.x & 7;
    const int chunk = blockIdx.x >> 3;
    const int i64 = (flags[1] == 0);
    const unsigned lo = (unsigned)(slice * SLICE_N);
    const int e0 = chunk * FCH;
    const int e1 = min(e0 + FCH, N_EDGES);
    for (int e = e0 + threadIdx.x; e < e1; e += 256) {
        unsigned d = edge_dst(ei, i64, e);
        if (d - lo < (unsigned)SLICE_N && d < (unsigned)N_NODES) {
            unsigned s = edge_src(ei, i64, e);
            if (s < (unsigned)N_NODES) {
                int pos = atomicAdd(&curs[d], 1);
                if ((unsigned)pos < (unsigned)N_EDGES) csr[pos] = (int)s;
            }
        }
    }
}

// ---------------- GEMM v2: h' = (in @ Wc[:,wcol0:+OUT]) * dinv, bf16 out ----
// 4x4 register tile / thread, all LDS traffic float4: per 4-k chunk a thread
// does 8 b128 LDS reads for 64 FMAs -> VALU-bound. Vectorized global staging.
template <int IN, int OUT, int NBLK, bool DYNIN>
__global__ __launch_bounds__(256) void gemm_kernel(
        const void* __restrict__ in, int inLD, const int* __restrict__ flags,
        const float* __restrict__ Wc, int WLD, int wcol0,
        const float* __restrict__ dinv, __hip_bfloat16* __restrict__ out) {
    constexpr int XLD = IN + 4;                    // float4-aligned pad
    constexpr int NT  = (NBLK / 4) * (OUT / 4);
    static_assert(NT == 256, "block must be 256 threads");
    __shared__ float Xs[NBLK * XLD];
    __shared__ float Ws[IN * OUT];
    const int tid = threadIdx.x;
    const int f32 = DYNIN ? flags[0] : 0;
    const int nbase = blockIdx.x * NBLK;
    for (int i = tid; i < IN * OUT / 4; i += NT) {
        const int k = i / (OUT / 4), cq = i % (OUT / 4);
        *(float4*)&Ws[k * OUT + cq * 4] = *(const float4*)&Wc[k * WLD + wcol0 + cq * 4];
    }
    for (int i = tid; i < NBLK * (IN / 4); i += NT) {
        const int nl = i / (IN / 4), kq = i % (IN / 4);
        const int n = nbase + nl;
        float4 v = {0.0f, 0.0f, 0.0f, 0.0f};
        if (n < N_NODES) {
            if (DYNIN && f32) {
                v = ((const float4*)((const float*)in + (size_t)n * inLD))[kq];
            } else {
                ushort4 u = ((const ushort4*)((const __hip_bfloat16*)in + (size_t)n * inLD))[kq];
                v.x = bf2f(u.x); v.y = bf2f(u.y); v.z = bf2f(u.z); v.w = bf2f(u.w);
            }
        }
        *(float4*)&Xs[nl * XLD + kq * 4] = v;
    }
    __syncthreads();
    const int gc = tid % (OUT / 4);
    const int gn = tid / (OUT / 4);
    float acc[4][4] = {};
    for (int k = 0; k < IN; k += 4) {
        const float4 w0 = *(const float4*)&Ws[(k + 0) * OUT + gc * 4];
        const float4 w1 = *(const float4*)&Ws[(k + 1) * OUT + gc * 4];
        const float4 w2 = *(const float4*)&Ws[(k + 2) * OUT + gc * 4];
        const float4 w3 = *(const float4*)&Ws[(k + 3) * OUT + gc * 4];
#pragma unroll
        for (int i = 0; i < 4; ++i) {
            const float4 xv = *(const float4*)&Xs[(gn * 4 + i) * XLD + k];
            acc[i][0] = fmaf(xv.x, w0.x, acc[i][0]);
            acc[i][0] = fmaf(xv.y, w1.x, acc[i][0]);
            acc[i][0] = fmaf(xv.z, w2.x, acc[i][0]);
            acc[i][0] = fmaf(xv.w, w3.x, acc[i][0]);
            acc[i][1] = fmaf(xv.x, w0.y, acc[i][1]);
            acc[i][1] = fmaf(xv.y, w1.y, acc[i][1]);
            acc[i][1] = fmaf(xv.z, w2.y, acc[i][1]);
            acc[i][1] = fmaf(xv.w, w3.y, acc[i][1]);
            acc[i][2] = fmaf(xv.x, w0.z, acc[i][2]);
            acc[i][2] = fmaf(xv.y, w1.z, acc[i][2]);
            acc[i][2] = fmaf(xv.z, w2.z, acc[i][2]);
            acc[i][2] = fmaf(xv.w, w3.z, acc[i][2]);
            acc[i][3] = fmaf(xv.x, w0.w, acc[i][3]);
            acc[i][3] = fmaf(xv.y, w1.w, acc[i][3]);
            acc[i][3] = fmaf(xv.z, w2.w, acc[i][3]);
            acc[i][3] = fmaf(xv.w, w3.w, acc[i][3]);
        }
    }
#pragma unroll
    for (int i = 0; i < 4; ++i) {
        const int n = nbase + gn * 4 + i;
        if (n >= N_NODES) continue;
        const float sc = dinv[n];
        __hip_bfloat162 p0, p1;
        p0.x = __float2bfloat16(acc[i][0] * sc);
        p0.y = __float2bfloat16(acc[i][1] * sc);
        p1.x = __float2bfloat16(acc[i][2] * sc);
        p1.y = __float2bfloat16(acc[i][3] * sc);
        __hip_bfloat162* dst = (__hip_bfloat162*)&out[(size_t)n * OUT + gc * 4];
        dst[0] = p0;
        dst[1] = p1;
    }
}

// ---------------- CSR aggregation ----------------
// SUBW-lane subwave per (node, 64/32-col group); WPN subwaves cover D cols.
// out[n,col] = dinv[n]*(sum_neighbors h'[s,col] + h'[n,col]) + b[col]
template <int D, int SUBW, int WPN, bool RELU>
__global__ __launch_bounds__(256) void agg_kernel(
        const int* __restrict__ offs, const int* __restrict__ csr,
        const float* __restrict__ dinv,
        const __hip_bfloat16* __restrict__ h,     // N x D, dinv-prescaled
        const float* __restrict__ bias,
        __hip_bfloat16* __restrict__ wsout,       // N x D bf16, or null
        void* __restrict__ gout, size_t gbase, int gLD, int gcol0,
        const int* __restrict__ flags) {
    const int lane = threadIdx.x & 63;
    const int wid  = threadIdx.x >> 6;
    constexpr int SPW = 64 / SUBW;                 // subwaves per wave
    constexpr int SPB = 4 * SPW;                   // subwaves per block
    const int gsw = blockIdx.x * SPB + wid * SPW + (SUBW == 64 ? 0 : (lane >> 5));
    const int n = gsw / WPN;
    if (n >= N_NODES) return;
    const int sl = lane & (SUBW - 1);
    const int col = (gsw % WPN) * SUBW + sl;
    float acc = __bfloat162float(h[(size_t)n * D + col]);   // self-loop term
    const int o0 = offs[n], o1 = offs[n + 1];
    for (int base = o0; base < o1; base += SUBW) {
        const int idx = base + sl;
        const int sid = (idx < o1) ? csr[idx] : 0;
        const int cnt = min(SUBW, o1 - base);
        int k = 0;
        for (; k + 8 <= cnt; k += 8) {
            int s[8];
#pragma unroll
            for (int u = 0; u < 8; ++u) s[u] = __shfl(sid, k + u, SUBW);
            float v[8];
#pragma unroll
            for (int u = 0; u < 8; ++u) v[u] = __bfloat162float(h[(size_t)s[u] * D + col]);
            acc += ((v[0] + v[1]) + (v[2] + v[3])) + ((v[4] + v[5]) + (v[6] + v[7]));
        }
        for (; k < cnt; ++k) {
            const int s = __shfl(sid, k, SUBW);
            acc += __bfloat162float(h[(size_t)s * D + col]);
        }
    }
    float v = fmaf(acc, dinv[n], bias[col]);
    if (RELU) v = fmaxf(v, 0.0f);
    if (wsout) wsout[(size_t)n * D + col] = __float2bfloat16(v);
    if (gout) {
        const size_t gi = gbase + (size_t)n * gLD + gcol0 + col;
        if (flags[0]) ((float*)gout)[gi] = v;
        else          ((__hip_bfloat16*)gout)[gi] = __float2bfloat16(v);
    }
}

// ---------------- launch ----------------
extern "C" void kernel_launch(void* const* d_in, const int* in_sizes, int n_in,
                              void* d_out, int out_size, void* d_ws, size_t ws_size,
                              hipStream_t stream) {
    const void* x  = d_in[0];
    const int* ei  = (const int*)d_in[1];
    const void* W1 = d_in[2]; const void* b1 = d_in[3];
    const void* W2 = d_in[4]; const void* b2 = d_in[5];
    const void* W3 = d_in[6]; const void* b3 = d_in[7];
    const void* W4 = d_in[8]; const void* b4 = d_in[9];

    char* ws = (char*)d_ws;
    int*   flags = (int*)(ws + OFF_FLAG);
    int*   deg   = (int*)(ws + OFF_DEG);
    float* dinv  = (float*)(ws + OFF_DINV);
    int*   offs  = (int*)(ws + OFF_OFFS);
    int*   curs  = (int*)(ws + OFF_CURS);
    int*   bsum  = (int*)(ws + OFF_BSUM);
    int*   boff  = bsum + 128;
    float* Wc    = (float*)(ws + OFF_WC);
    int*   csr   = (int*)(ws + OFF_CSR);
    __hip_bfloat16* A = (__hip_bfloat16*)(ws + OFF_A);
    __hip_bfloat16* B = (__hip_bfloat16*)(ws + OFF_B);

    // setup: flags, weights, degrees, dinv, CSR
    hipMemsetAsync(flags, 0, 2 * sizeof(int), stream);
    hipMemsetAsync(deg, 0, (size_t)N_NODES * sizeof(int), stream);
    detect_kernel<<<1, 256, 0, stream>>>((const unsigned*)W1, (const unsigned*)ei, flags);
    convw_kernel<<<(WC_TOT + 255) / 256, 256, 0, stream>>>(W1, b1, W2, b2, W3, b3, W4, b4,
                                                           flags, Wc);
    deg_kernel<<<8 * NCH, 256, 0, stream>>>(ei, flags, deg);
    dinv_kernel<<<(N_NODES + 255) / 256, 256, 0, stream>>>(deg, dinv);
    scan1_kernel<<<SCAN_G, SCAN_B, 0, stream>>>(deg, bsum);
    scan2_kernel<<<1, 128, 0, stream>>>(bsum, boff);
    scan3_kernel<<<SCAN_G, SCAN_B, 0, stream>>>(deg, boff, offs, curs);
    fill_kernel<<<8 * NCH, 256, 0, stream>>>(ei, flags, curs, csr);

    // ---- Layer 1: 128 -> 64, ReLU.  x -> A (h'), aggregate -> B (act1) ----
    gemm_kernel<128, 64, 64, true><<<(N_NODES + 63) / 64, 256, 0, stream>>>(
        x, 128, flags, Wc + WC_W1, 64, 0, dinv, A);
    agg_kernel<64, 64, 1, true><<<(N_NODES + 3) / 4, 256, 0, stream>>>(
        offs, csr, dinv, A, Wc + WC_B1, B, nullptr, 0, 0, 0, flags);

    // ---- Layer 2: 64 -> 32 (z).  B -> A (h'), aggregate -> B (z) + d_out z ----
    gemm_kernel<64, 32, 128, false><<<(N_NODES + 127) / 128, 256, 0, stream>>>(
        B, 64, flags, Wc + WC_W2, 32, 0, dinv, A);
    agg_kernel<32, 32, 1, false><<<(N_NODES + 7) / 8, 256, 0, stream>>>(
        offs, csr, dinv, A, Wc + WC_B2, B, d_out, (size_t)N_NODES * 128, 32, 0, flags);

    // ---- Layer 3: 32 -> 64, ReLU.  B (z) -> A (h'), aggregate -> B (act3) ----
    gemm_kernel<32, 64, 64, false><<<(N_NODES + 63) / 64, 256, 0, stream>>>(
        B, 32, flags, Wc + WC_W3, 64, 0, dinv, A);
    agg_kernel<64, 64, 1, true><<<(N_NODES + 3) / 4, 256, 0, stream>>>(
        offs, csr, dinv, A, Wc + WC_B3, B, nullptr, 0, 0, 0, flags);

    // ---- Layer 4: 64 -> 128 single pass.  B -> A (h', N x 128), aggregate -> x_rec ----
    gemm_kernel<64, 128, 32, false><<<(N_NODES + 31) / 32, 256, 0, stream>>>(
        B, 64, flags, Wc + WC_W4, 128, 0, dinv, A);
    agg_kernel<128, 64, 2, false><<<(2 * N_NODES + 3) / 4, 256, 0, stream>>>(
        offs, csr, dinv, A, Wc + WC_B4, nullptr, d_out, 0, 128, 0, flags);
}

// Round 6
// 620.711 us; speedup vs baseline: 3.5200x; 1.0980x over previous
//
#include <hip/hip_runtime.h>
#include <hip/hip_bf16.h>

constexpr int N_NODES = 100000;
constexpr int N_EDGES = 1600000;
constexpr int SCAN_B  = 1024;
constexpr int SCAN_G  = (N_NODES + SCAN_B) / SCAN_B;   // 98 blocks covers N+1 elements
constexpr int FCH     = 8192;                          // edges per chunk (slice kernels)
constexpr int NCH     = (N_EDGES + FCH - 1) / FCH;     // 196
constexpr int SLICE_N = N_NODES / 8;                   // 12500

// ---- workspace layout (byte offsets), total ~34 MB ----
constexpr size_t OFF_FLAG = 0;                 // 2 ints: [0]=fp32 floats, [1]=int32 edges
constexpr size_t OFF_DEG  = 4    * 1024;       // int[N]
constexpr size_t OFF_DINV = 408  * 1024;       // float[N]
constexpr size_t OFF_OFFS = 812  * 1024;       // int[N+1]
constexpr size_t OFF_CURS = 1216 * 1024;       // int[N]
constexpr size_t OFF_BSUM = 1620 * 1024;       // int[128] bsum + int[128] boff
constexpr size_t OFF_WC   = 1624 * 1024;       // float[20768]
constexpr size_t OFF_CSR  = 1712 * 1024;       // int[E] (6.4 MB)
constexpr size_t OFF_A    = 8192 * 1024;       // bf16 N*64 (12.8 MB)
constexpr size_t OFF_B    = 21504ul * 1024;    // bf16 N*64 (12.8 MB)

// Wc float offsets
constexpr int WC_W1 = 0, WC_W2 = 8192, WC_W3 = 10240, WC_W4 = 12288;
constexpr int WC_B1 = 20480, WC_B2 = 20544, WC_B3 = 20576, WC_B4 = 20640;
constexpr int WC_TOT = 20768;

__device__ __forceinline__ float bf2f(unsigned short b) {
    union { unsigned u; float f; } c; c.u = ((unsigned)b) << 16; return c.f;
}

// ---------------- dtype detection (proven) ----------------
__global__ void detect_kernel(const unsigned* __restrict__ w1raw,
                              const unsigned* __restrict__ eiraw,
                              int* __restrict__ flags) {
    const int t = threadIdx.x;  // 1 block x 256
    int f32 = 0, i32 = 0;
    for (int i = t; i < 1024; i += 256) {
        unsigned lo = w1raw[i] & 0xFFFFu;
        if ((lo & 0x7F80u) >= 0x3F00u) f32 = 1;    // bf16 glorot can't have big low-half exp
    }
    for (int i = t; i < 4096; i += 256)
        if ((i & 1) && eiraw[i] != 0u) i32 = 1;    // int64 high words are all zero
    if (f32) atomicOr(&flags[0], 1);
    if (i32) atomicOr(&flags[1], 1);
}

__device__ __forceinline__ unsigned edge_src(const int* ei, int i64, int e) {
    return (unsigned)(i64 ? ei[2 * (size_t)e] : ei[e]);
}
__device__ __forceinline__ unsigned edge_dst(const int* ei, int i64, int e) {
    return (unsigned)(i64 ? ei[2 * (size_t)N_EDGES + 2 * (size_t)e]
                          : ei[(size_t)N_EDGES + e]);
}

// ---------------- weights -> fp32 ws copies ----------------
__global__ void convw_kernel(const void* W1, const void* b1, const void* W2, const void* b2,
                             const void* W3, const void* b3, const void* W4, const void* b4,
                             const int* __restrict__ flags, float* __restrict__ Wc) {
    int i = blockIdx.x * blockDim.x + threadIdx.x;
    if (i >= WC_TOT) return;
    const void* src; int off;
    if      (i < WC_W2) { src = W1; off = i; }
    else if (i < WC_W3) { src = W2; off = i - WC_W2; }
    else if (i < WC_W4) { src = W3; off = i - WC_W3; }
    else if (i < WC_B1) { src = W4; off = i - WC_W4; }
    else if (i < WC_B2) { src = b1; off = i - WC_B1; }
    else if (i < WC_B3) { src = b2; off = i - WC_B2; }
    else if (i < WC_B4) { src = b3; off = i - WC_B3; }
    else                { src = b4; off = i - WC_B4; }
    Wc[i] = flags[0] ? ((const float*)src)[off]
                     : __bfloat162float(((const __hip_bfloat16*)src)[off]);
}

// ---------------- slice-local degree histogram (XCD-affine, proven r5) ----------------
__global__ void deg_kernel(const int* __restrict__ ei, const int* __restrict__ flags,
                           int* __restrict__ deg) {
    const int slice = blockIdx.x & 7;
    const int chunk = blockIdx.x >> 3;
    const int i64 = (flags[1] == 0);
    const unsigned lo = (unsigned)(slice * SLICE_N);
    const int e0 = chunk * FCH;
    const int e1 = min(e0 + FCH, N_EDGES);
    for (int e = e0 + threadIdx.x; e < e1; e += 256) {
        unsigned d = edge_dst(ei, i64, e);
        if (d - lo < (unsigned)SLICE_N && d < (unsigned)N_NODES) atomicAdd(&deg[d], 1);
    }
}

__global__ void dinv_kernel(const int* __restrict__ deg, float* __restrict__ dinv) {
    int n = blockIdx.x * blockDim.x + threadIdx.x;
    if (n < N_NODES) dinv[n] = rsqrtf((float)deg[n] + 1.0f);
}

// ---------------- hierarchical exclusive scan of deg -> offsets ----------------
__global__ __launch_bounds__(1024) void scan1_kernel(const int* __restrict__ deg,
                                                     int* __restrict__ bsum) {
    const int i = blockIdx.x * SCAN_B + threadIdx.x;
    const int lane = threadIdx.x & 63, wid = threadIdx.x >> 6;
    int v = (i < N_NODES) ? deg[i] : 0;
    for (int o = 32; o > 0; o >>= 1) v += __shfl_down(v, o, 64);
    __shared__ int ws[16];
    if (lane == 0) ws[wid] = v;
    __syncthreads();
    if (wid == 0) {
        int t = (lane < 16) ? ws[lane] : 0;
        for (int o = 8; o > 0; o >>= 1) t += __shfl_down(t, o, 64);
        if (lane == 0) bsum[blockIdx.x] = t;
    }
}

__global__ void scan2_kernel(const int* __restrict__ bsum, int* __restrict__ boff) {
    const int t = threadIdx.x;   // 1 block x 128
    __shared__ int tmp[128];
    int v = (t < SCAN_G) ? bsum[t] : 0;
    tmp[t] = v;
    __syncthreads();
    for (int o = 1; o < 128; o <<= 1) {
        int a = (t >= o) ? tmp[t - o] : 0;
        __syncthreads();
        tmp[t] += a;
        __syncthreads();
    }
    boff[t] = tmp[t] - v;        // exclusive
}

__global__ __launch_bounds__(1024) void scan3_kernel(const int* __restrict__ deg,
                                                     const int* __restrict__ boff,
                                                     int* __restrict__ offs,
                                                     int* __restrict__ curs) {
    const int i = blockIdx.x * SCAN_B + threadIdx.x;
    const int lane = threadIdx.x & 63, wid = threadIdx.x >> 6;
    int v = (i < N_NODES) ? deg[i] : 0;
    int incl = v;
    for (int o = 1; o < 64; o <<= 1) {
        int t = __shfl_up(incl, (unsigned)o, 64);
        if (lane >= o) incl += t;
    }
    __shared__ int wsum[16], woff[16];
    if (lane == 63) wsum[wid] = incl;
    __syncthreads();
    if (wid == 0 && lane < 16) {
        int u = wsum[lane];
        int uin = u;
        for (int o = 1; o < 16; o <<= 1) {
            int t = __shfl_up(uin, (unsigned)o, 64);
            if (lane >= o) uin += t;
        }
        woff[lane] = uin - u;
    }
    __syncthreads();
    const int excl = incl - v + woff[wid] + boff[blockIdx.x];
    if (i <= N_NODES) {
        offs[i] = excl;
        if (i < N_NODES) curs[i] = excl;
    }
}

// ---------------- slice-local CSR fill (XCD-affine, proven r5) ----------------
__global__ void fill_kernel(const int* __restrict__ ei, const int* __restrict__ flags,
                            int* __restrict__ curs, int* __restrict__ csr) {
    const int slice = blockIdx.x & 7;
    const int chunk = blockIdx.x >> 3;
    const int i64 = (flags[1] == 0);
    const unsigned lo = (unsigned)(slice * SLICE_N);
    const int e0 = chunk * FCH;
    const int e1 = min(e0 + FCH, N_EDGES);
    for (int e = e0 + threadIdx.x; e < e1; e += 256) {
        unsigned d = edge_dst(ei, i64, e);
        if (d - lo < (unsigned)SLICE_N && d < (unsigned)N_NODES) {
            unsigned s = edge_src(ei, i64, e);
            if (s < (unsigned)N_NODES) {
                int pos = atomicAdd(&curs[d], 1);
                if ((unsigned)pos < (unsigned)N_EDGES) csr[pos] = (int)s;
            }
        }
    }
}

// ---------------- GEMM: out = epi(in @ Wc + bias) [*dinv] ----------------
// 4x4 register tile / thread, all LDS traffic float4.
// SCALE: multiply result by dinv[n] (prescale for a following aggregation).
template <int IN, int OUT, int NBLK, bool DYNIN, bool RELU, bool BIAS, bool SCALE>
__global__ __launch_bounds__(256) void gemm_kernel(
        const void* __restrict__ in, int inLD, const int* __restrict__ flags,
        const float* __restrict__ Wc, int WLD, const float* __restrict__ bias,
        const float* __restrict__ dinv,
        __hip_bfloat16* __restrict__ wsout,            // bf16 ws, or null
        void* __restrict__ gout, int gLD) {            // dtype-branch global, or null
    constexpr int XLD = IN + 4;
    constexpr int NT  = (NBLK / 4) * (OUT / 4);
    static_assert(NT == 256, "block must be 256 threads");
    __shared__ float Xs[NBLK * XLD];
    __shared__ float Ws[IN * OUT];
    const int tid = threadIdx.x;
    const int f32 = flags[0];
    const int nbase = blockIdx.x * NBLK;
    for (int i = tid; i < IN * OUT / 4; i += NT) {
        const int k = i / (OUT / 4), cq = i % (OUT / 4);
        *(float4*)&Ws[k * OUT + cq * 4] = *(const float4*)&Wc[k * WLD + cq * 4];
    }
    for (int i = tid; i < NBLK * (IN / 4); i += NT) {
        const int nl = i / (IN / 4), kq = i % (IN / 4);
        const int n = nbase + nl;
        float4 v = {0.0f, 0.0f, 0.0f, 0.0f};
        if (n < N_NODES) {
            if (DYNIN && f32) {
                v = ((const float4*)((const float*)in + (size_t)n * inLD))[kq];
            } else {
                ushort4 u = ((const ushort4*)((const __hip_bfloat16*)in + (size_t)n * inLD))[kq];
                v.x = bf2f(u.x); v.y = bf2f(u.y); v.z = bf2f(u.z); v.w = bf2f(u.w);
            }
        }
        *(float4*)&Xs[nl * XLD + kq * 4] = v;
    }
    __syncthreads();
    const int gc = tid % (OUT / 4);
    const int gn = tid / (OUT / 4);
    float acc[4][4] = {};
    for (int k = 0; k < IN; k += 4) {
        const float4 w0 = *(const float4*)&Ws[(k + 0) * OUT + gc * 4];
        const float4 w1 = *(const float4*)&Ws[(k + 1) * OUT + gc * 4];
        const float4 w2 = *(const float4*)&Ws[(k + 2) * OUT + gc * 4];
        const float4 w3 = *(const float4*)&Ws[(k + 3) * OUT + gc * 4];
#pragma unroll
        for (int i = 0; i < 4; ++i) {
            const float4 xv = *(const float4*)&Xs[(gn * 4 + i) * XLD + k];
            acc[i][0] = fmaf(xv.x, w0.x, acc[i][0]);
            acc[i][0] = fmaf(xv.y, w1.x, acc[i][0]);
            acc[i][0] = fmaf(xv.z, w2.x, acc[i][0]);
            acc[i][0] = fmaf(xv.w, w3.x, acc[i][0]);
            acc[i][1] = fmaf(xv.x, w0.y, acc[i][1]);
            acc[i][1] = fmaf(xv.y, w1.y, acc[i][1]);
            acc[i][1] = fmaf(xv.z, w2.y, acc[i][1]);
            acc[i][1] = fmaf(xv.w, w3.y, acc[i][1]);
            acc[i][2] = fmaf(xv.x, w0.z, acc[i][2]);
            acc[i][2] = fmaf(xv.y, w1.z, acc[i][2]);
            acc[i][2] = fmaf(xv.z, w2.z, acc[i][2]);
            acc[i][2] = fmaf(xv.w, w3.z, acc[i][2]);
            acc[i][3] = fmaf(xv.x, w0.w, acc[i][3]);
            acc[i][3] = fmaf(xv.y, w1.w, acc[i][3]);
            acc[i][3] = fmaf(xv.z, w2.w, acc[i][3]);
            acc[i][3] = fmaf(xv.w, w3.w, acc[i][3]);
        }
    }
    float4 bv = {0.0f, 0.0f, 0.0f, 0.0f};
    if (BIAS) bv = *(const float4*)&bias[gc * 4];
#pragma unroll
    for (int i = 0; i < 4; ++i) {
        const int n = nbase + gn * 4 + i;
        if (n >= N_NODES) continue;
        float v0 = acc[i][0], v1 = acc[i][1], v2 = acc[i][2], v3 = acc[i][3];
        if (BIAS) { v0 += bv.x; v1 += bv.y; v2 += bv.z; v3 += bv.w; }
        if (RELU) {
            v0 = fmaxf(v0, 0.0f); v1 = fmaxf(v1, 0.0f);
            v2 = fmaxf(v2, 0.0f); v3 = fmaxf(v3, 0.0f);
        }
        if (SCALE) {
            const float sc = dinv[n];
            v0 *= sc; v1 *= sc; v2 *= sc; v3 *= sc;
        }
        if (wsout) {
            __hip_bfloat162 p0, p1;
            p0.x = __float2bfloat16(v0); p0.y = __float2bfloat16(v1);
            p1.x = __float2bfloat16(v2); p1.y = __float2bfloat16(v3);
            __hip_bfloat162* dst = (__hip_bfloat162*)&wsout[(size_t)n * OUT + gc * 4];
            dst[0] = p0; dst[1] = p1;
        }
        if (gout) {
            const size_t gi = (size_t)n * gLD + gc * 4;
            if (f32) {
                float4 o = {v0, v1, v2, v3};
                *(float4*)&((float*)gout)[gi] = o;
            } else {
                __hip_bfloat162 p0, p1;
                p0.x = __float2bfloat16(v0); p0.y = __float2bfloat16(v1);
                p1.x = __float2bfloat16(v2); p1.y = __float2bfloat16(v3);
                __hip_bfloat162* dst = (__hip_bfloat162*)&((__hip_bfloat16*)gout)[gi];
                dst[0] = p0; dst[1] = p1;
            }
        }
    }
}

// ---------------- CSR aggregation ----------------
// out[n,col] = dinv[n]*(sum_{s in N(n)} h[s,col] + h[n,col]) (+bias) [+relu]
// h must be pre-scaled by dinv on the source side.
template <int D, int SUBW, bool RELU>
__global__ __launch_bounds__(256) void agg_kernel(
        const int* __restrict__ offs, const int* __restrict__ csr,
        const float* __restrict__ dinv,
        const __hip_bfloat16* __restrict__ h,     // N x D, dinv-prescaled
        const float* __restrict__ bias,           // null -> 0
        __hip_bfloat16* __restrict__ wsout,       // unscaled bf16, or null
        __hip_bfloat16* __restrict__ wsout_sc,    // *dinv[n] bf16 (prescale next), or null
        void* __restrict__ gout, size_t gbase, int gLD,   // dtype-branch global, or null
        const int* __restrict__ flags) {
    const int lane = threadIdx.x & 63;
    const int wid  = threadIdx.x >> 6;
    constexpr int SPW = 64 / SUBW;                 // subwaves per wave
    constexpr int SPB = 4 * SPW;                   // subwaves per block
    const int n = blockIdx.x * SPB + wid * SPW + (SUBW == 64 ? 0 : (lane >> 5));
    if (n >= N_NODES) return;
    const int sl = lane & (SUBW - 1);
    const int col = sl;
    float acc = __bfloat162float(h[(size_t)n * D + col]);   // self-loop term
    const int o0 = offs[n], o1 = offs[n + 1];
    for (int base = o0; base < o1; base += SUBW) {
        const int idx = base + sl;
        const int sid = (idx < o1) ? csr[idx] : 0;
        const int cnt = min(SUBW, o1 - base);
        int k = 0;
        for (; k + 8 <= cnt; k += 8) {
            int s[8];
#pragma unroll
            for (int u = 0; u < 8; ++u) s[u] = __shfl(sid, k + u, SUBW);
            float v[8];
#pragma unroll
            for (int u = 0; u < 8; ++u) v[u] = __bfloat162float(h[(size_t)s[u] * D + col]);
            acc += ((v[0] + v[1]) + (v[2] + v[3])) + ((v[4] + v[5]) + (v[6] + v[7]));
        }
        for (; k < cnt; ++k) {
            const int s = __shfl(sid, k, SUBW);
            acc += __bfloat162float(h[(size_t)s * D + col]);
        }
    }
    const float di = dinv[n];
    float v = acc * di;
    if (bias) v += bias[col];
    if (RELU) v = fmaxf(v, 0.0f);
    if (wsout)    wsout[(size_t)n * D + col]    = __float2bfloat16(v);
    if (wsout_sc) wsout_sc[(size_t)n * D + col] = __float2bfloat16(v * di);
    if (gout) {
        const size_t gi = gbase + (size_t)n * gLD + col;
        if (flags[0]) ((float*)gout)[gi] = v;
        else          ((__hip_bfloat16*)gout)[gi] = __float2bfloat16(v);
    }
}

// ---------------- launch ----------------
extern "C" void kernel_launch(void* const* d_in, const int* in_sizes, int n_in,
                              void* d_out, int out_size, void* d_ws, size_t ws_size,
                              hipStream_t stream) {
    const void* x  = d_in[0];
    const int* ei  = (const int*)d_in[1];
    const void* W1 = d_in[2]; const void* b1 = d_in[3];
    const void* W2 = d_in[4]; const void* b2 = d_in[5];
    const void* W3 = d_in[6]; const void* b3 = d_in[7];
    const void* W4 = d_in[8]; const void* b4 = d_in[9];

    char* ws = (char*)d_ws;
    int*   flags = (int*)(ws + OFF_FLAG);
    int*   deg   = (int*)(ws + OFF_DEG);
    float* dinv  = (float*)(ws + OFF_DINV);
    int*   offs  = (int*)(ws + OFF_OFFS);
    int*   curs  = (int*)(ws + OFF_CURS);
    int*   bsum  = (int*)(ws + OFF_BSUM);
    int*   boff  = bsum + 128;
    float* Wc    = (float*)(ws + OFF_WC);
    int*   csr   = (int*)(ws + OFF_CSR);
    __hip_bfloat16* A = (__hip_bfloat16*)(ws + OFF_A);
    __hip_bfloat16* B = (__hip_bfloat16*)(ws + OFF_B);

    // setup: flags, weights, degrees, dinv, CSR
    hipMemsetAsync(flags, 0, 2 * sizeof(int), stream);
    hipMemsetAsync(deg, 0, (size_t)N_NODES * sizeof(int), stream);
    detect_kernel<<<1, 256, 0, stream>>>((const unsigned*)W1, (const unsigned*)ei, flags);
    convw_kernel<<<(WC_TOT + 255) / 256, 256, 0, stream>>>(W1, b1, W2, b2, W3, b3, W4, b4,
                                                           flags, Wc);
    deg_kernel<<<8 * NCH, 256, 0, stream>>>(ei, flags, deg);
    dinv_kernel<<<(N_NODES + 255) / 256, 256, 0, stream>>>(deg, dinv);
    scan1_kernel<<<SCAN_G, SCAN_B, 0, stream>>>(deg, bsum);
    scan2_kernel<<<1, 128, 0, stream>>>(bsum, boff);
    scan3_kernel<<<SCAN_G, SCAN_B, 0, stream>>>(deg, boff, offs, curs);
    fill_kernel<<<8 * NCH, 256, 0, stream>>>(ei, flags, curs, csr);

    __hip_bfloat16* out_z32 = nullptr;   // handled via gbase on d_out

    // ---- Layer 1: h1' = (x@W1)*dinv -> A; act1 = ReLU(agg) -> B ----
    gemm_kernel<128, 64, 64, true, false, false, true><<<(N_NODES + 63) / 64, 256, 0, stream>>>(
        x, 128, flags, Wc + WC_W1, 64, nullptr, dinv, A, nullptr, 0);
    agg_kernel<64, 64, true><<<(N_NODES + 3) / 4, 256, 0, stream>>>(
        offs, csr, dinv, A, Wc + WC_B1, B, nullptr, nullptr, 0, 0, flags);

    // ---- Layer 2: h2' = (act1@W2)*dinv -> A; z = agg -> d_out, zp = z*dinv -> B ----
    gemm_kernel<64, 32, 128, false, false, false, true><<<(N_NODES + 127) / 128, 256, 0, stream>>>(
        B, 64, flags, Wc + WC_W2, 32, nullptr, dinv, A, nullptr, 0);
    agg_kernel<32, 32, false><<<(N_NODES + 7) / 8, 256, 0, stream>>>(
        offs, csr, dinv, A, Wc + WC_B2, nullptr, B,
        d_out, (size_t)N_NODES * 128, 32, flags);

    // ---- Layer 3 (agg-first): t3 = agg(zp) -> A; act3p = ReLU(t3@W3+b3)*dinv -> B ----
    agg_kernel<32, 32, false><<<(N_NODES + 7) / 8, 256, 0, stream>>>(
        offs, csr, dinv, B, nullptr, A, nullptr, nullptr, 0, 0, flags);
    gemm_kernel<32, 64, 64, false, true, true, true><<<(N_NODES + 63) / 64, 256, 0, stream>>>(
        A, 32, flags, Wc + WC_W3, 64, Wc + WC_B3, dinv, B, nullptr, 0);

    // ---- Layer 4 (agg-first): t4 = agg(act3p) -> A; x_rec = t4@W4+b4 -> d_out ----
    agg_kernel<64, 64, false><<<(N_NODES + 3) / 4, 256, 0, stream>>>(
        offs, csr, dinv, B, nullptr, A, nullptr, nullptr, 0, 0, flags);
    gemm_kernel<64, 128, 32, false, false, true, false><<<(N_NODES + 31) / 32, 256, 0, stream>>>(
        A, 64, flags, Wc + WC_W4, 128, Wc + WC_B4, dinv, nullptr, d_out, 128);
}